// Round 8
// baseline (816.221 us; speedup 1.0000x reference)
//
#include <hip/hip_runtime.h>
#include <math.h>

#define B 4
#define NPTS 300000
#define G 15
#define G3 3375
#define SCENE_FLOATS (B*12*G3)   // 162000
#define NREP 8                   // == XCD count; required for L2-local atomics
#define NB_TAIL 64               // blocks in fused tail kernel

__device__ __forceinline__ float eluf(float v) {
    return v > 0.0f ? v : __expf(v) - 1.0f;
}

// Coherence-point data movement: relaxed agent-scope atomics bypass the
// non-coherent per-XCD L2s per-access -> no wbl2/invl2 fences needed anywhere.
__device__ __forceinline__ float aload(const float* p) {
    return __hip_atomic_load((float*)p, __ATOMIC_RELAXED, __HIP_MEMORY_SCOPE_AGENT);
}
__device__ __forceinline__ void astore(float* p, float v) {
    __hip_atomic_store(p, v, __ATOMIC_RELAXED, __HIP_MEMORY_SCOPE_AGENT);
}

// ---------------------------------------------------------------------------
// Stage 1: per-point MLP (wave-uniform s_load weights) -> scatter-max into
// the replica belonging to this block's PHYSICAL XCD, using non-bypassing
// (L2-executed) atomics. All contenders for a replica are on its XCD, so the
// XCD L2 keeps them coherent; kernel-end release writes replicas back.
// ---------------------------------------------------------------------------
__global__ __launch_bounds__(256)
void point_kernel(const float* __restrict__ P0,   // inputs  (set 0)
                  const float* __restrict__ P1,   // goals   (set 1)
                  const float* __restrict__ P2,   // backgrounds (set 2)
                  const float* __restrict__ W1, const float* __restrict__ b1,
                  const float* __restrict__ W2, const float* __restrict__ b2,
                  const float* __restrict__ W3, const float* __restrict__ b3,
                  float* __restrict__ scenesR, int nrep, int lscope)
{
    int b   = blockIdx.y;
    int set = blockIdx.z;
    const float* P = (set == 0) ? P0 : ((set == 1) ? P1 : P2);

    unsigned xcc = 0;
    if (lscope)
        asm volatile("s_getreg_b32 %0, hwreg(HW_REG_XCC_ID)" : "=s"(xcc));

    int idx = blockIdx.x * 256 + threadIdx.x;
    if (idx >= NPTS) return;

    const float* p = P + ((size_t)b * NPTS + idx) * 3;
    float px = p[0], py = p[1], pz = p[2];

    const float HI = 14.9999f;  // GZ - 1e-4
    float cx = floorf(fminf(fmaxf(px, 0.0f), HI));
    float cy = floorf(fminf(fmaxf(py, 0.0f), HI));
    float cz = floorf(fminf(fmaxf(pz, 0.0f), HI));

    float x[12];
    x[0] = px - (cx + 0.5f); x[1] = py - (cy + 0.5f); x[2] = pz - (cz + 0.5f);
    x[3] = px - cx;          x[4] = py - cy;          x[5] = pz - cz;
    x[6] = px - (cx + 1.0f); x[7] = py - (cy + 1.0f); x[8] = pz - (cz + 1.0f);
    x[9]  = sqrtf(x[0]*x[0] + x[1]*x[1] + x[2]*x[2]);
    x[10] = sqrtf(x[3]*x[3] + x[4]*x[4] + x[5]*x[5]);
    x[11] = sqrtf(x[6]*x[6] + x[7]*x[7] + x[8]*x[8]);

    float h1[16];
#pragma unroll
    for (int j = 0; j < 16; ++j) {
        float s = b1[j];
#pragma unroll
        for (int k = 0; k < 12; ++k) s = fmaf(x[k], W1[k*16 + j], s);
        h1[j] = eluf(s);
    }
    float h2[16];
#pragma unroll
    for (int j = 0; j < 16; ++j) {
        float s = b2[j];
#pragma unroll
        for (int k = 0; k < 16; ++k) s = fmaf(h1[k], W2[k*16 + j], s);
        h2[j] = eluf(s);
    }
    float o[4];
#pragma unroll
    for (int j = 0; j < 4; ++j) {
        float s = b3[j];
#pragma unroll
        for (int k = 0; k < 16; ++k) s = fmaf(h2[k], W3[k*4 + j], s);
        o[j] = s;
    }

    int cell = (((int)cx) * G + (int)cy) * G + (int)cz;
    int rep  = (int)(xcc & (unsigned)(nrep - 1));
    float* dstf = scenesR + (size_t)rep * SCENE_FLOATS
                          + (size_t)(b * 12 + set * 4) * G3 + cell;
#pragma unroll
    for (int c = 0; c < 4; ++c) {
        float v = o[c];
        if (v > 0.0f) {   // grid floor is 0; positive floats order like uints
            unsigned* a = (unsigned*)(dstf + c * G3);
            if (lscope)   // L2-executed RMW (coherent within this XCD)
                __hip_atomic_fetch_max(a, __float_as_uint(v),
                                       __ATOMIC_RELAXED, __HIP_MEMORY_SCOPE_WORKGROUP);
            else          // coherence-point RMW (safe for shared replicas)
                atomicMax(a, __float_as_uint(v));
        }
    }
}

// ---------------------------------------------------------------------------
// Fence-free grid barrier: __syncthreads drains vmcnt (so all prior
// L2-bypassing stores are durable at the coherence point), then one relaxed
// arrival add; block 0 alone polls the counter and publishes a go flag that
// the rest poll read-only. No cache-maintenance ops at all.
// ---------------------------------------------------------------------------
__device__ __forceinline__ void grid_barrier(unsigned* cnt, unsigned* go, int nb) {
    __syncthreads();
    if (threadIdx.x == 0) {
        __hip_atomic_fetch_add(cnt, 1u, __ATOMIC_RELAXED, __HIP_MEMORY_SCOPE_AGENT);
        if (blockIdx.x == 0) {
            while (__hip_atomic_load(cnt, __ATOMIC_RELAXED, __HIP_MEMORY_SCOPE_AGENT)
                   < (unsigned)nb)
                __builtin_amdgcn_s_sleep(1);
            __hip_atomic_store(go, 1u, __ATOMIC_RELAXED, __HIP_MEMORY_SCOPE_AGENT);
        } else {
            while (__hip_atomic_load(go, __ATOMIC_RELAXED, __HIP_MEMORY_SCOPE_AGENT) == 0u)
                __builtin_amdgcn_s_sleep(8);
        }
    }
    __syncthreads();
}

// ---------------------------------------------------------------------------
// Fused tail, 64 blocks x 256 threads, 7 fence-free barriers.
// block = (b, co, od-half); thread = (odl, oh, ow) -> 1 output element.
// conv1 fuses the replica max-reduce into its LDS staging (per-ci tiles).
// All cross-phase data via aload/astore (coherence point).
// ---------------------------------------------------------------------------
__global__ __launch_bounds__(256)
void tail_kernel(const float* __restrict__ scenesR, int nrep,
                 const float* __restrict__ conv1_w, const float* __restrict__ conv1_b,
                 const float* __restrict__ bn1_g,   const float* __restrict__ bn1_b,
                 const float* __restrict__ convs_w, const float* __restrict__ convs_b,
                 const float* __restrict__ bns_g,   const float* __restrict__ bns_b,
                 float* __restrict__ yA, float* __restrict__ yB,
                 float* __restrict__ stats,          // 7*16 floats, pre-zeroed
                 unsigned* __restrict__ bar,         // 7*32 slots, pre-zeroed
                 float* __restrict__ outp)
{
    __shared__ float sIn[9216];   // conv_s: [ci][8][12*12]; conv1 tile: 11*19*19=3971
    __shared__ float sred[256];
    __shared__ float sscale[8], sshift[8];

    const int bx  = blockIdx.x;
    const int tid = threadIdx.x;
    const int odh = bx & 1, co = (bx >> 1) & 7, b = bx >> 4;
    const int ow = tid & 7, oh = (tid >> 3) & 7, odl = tid >> 6;  // odl 0..3
    const int od = odh * 4 + odl;
    const int s2 = od * 64 + oh * 8 + ow;

    // ---- phase 1: conv1 (stride 2, pad 2) with fused replica max ---------
    float acc = conv1_b[co];
    for (int ci = 0; ci < 12; ++ci) {
        // padded tile[11][19][19] for id in [8*odh-2, 8*odh+8]
        for (int s = tid; s < 3971; s += 256) {
            int lp = s / 361, r = s % 361;
            int rh = r / 19, rw = r % 19;
            int id = 8 * odh - 2 + lp, ih = rh - 2, iw = rw - 2;
            float v = 0.0f;
            if ((unsigned)id < 15u && (unsigned)ih < 15u && (unsigned)iw < 15u) {
                size_t base = (size_t)(b * 12 + ci) * G3 + (id * 15 + ih) * 15 + iw;
                for (int rp = 0; rp < nrep; ++rp)   // plain loads: prev-kernel data
                    v = fmaxf(v, scenesR[(size_t)rp * SCENE_FLOATS + base]);
            }
            sIn[s] = v;
        }
        __syncthreads();
        const float* wc = conv1_w + (size_t)(co * 12 + ci) * 125;
#pragma unroll
        for (int kd = 0; kd < 5; ++kd) {
            int lp = 2 * odl + kd;   // local plane
#pragma unroll
            for (int kh = 0; kh < 5; ++kh) {
                const float* row = &sIn[lp * 361 + (2 * oh + kh) * 19 + 2 * ow];
                const float* wr  = wc + kd * 25 + kh * 5;
#pragma unroll
                for (int kw = 0; kw < 5; ++kw) acc = fmaf(row[kw], wr[kw], acc);
            }
        }
        __syncthreads();
    }
    astore(&yA[(size_t)(b * 8 + co) * 512 + s2], acc);
    {
        float sum = acc, sq = acc * acc;
#pragma unroll
        for (int o = 32; o > 0; o >>= 1) {
            sum += __shfl_down(sum, o, 64);
            sq  += __shfl_down(sq,  o, 64);
        }
        if ((tid & 63) == 0) { sred[tid >> 6] = sum; sred[4 + (tid >> 6)] = sq; }
        __syncthreads();
        if (tid == 0) {
            atomicAdd(&stats[co],     sred[0] + sred[1] + sred[2] + sred[3]);
            atomicAdd(&stats[8 + co], sred[4] + sred[5] + sred[6] + sred[7]);
        }
    }
    grid_barrier(bar + 0 * 32, bar + 0 * 32 + 16, NB_TAIL);

    // ---- phases 2..7: six BN+ELU+conv(stride1,pad2) layers ----------------
    const float* cur = yA;
    float* nxt = yB;
    for (int li = 1; li <= 6; ++li) {
        const float* g   = (li == 1) ? bn1_g : (bns_g + (li - 2) * 8);
        const float* bet = (li == 1) ? bn1_b : (bns_b + (li - 2) * 8);
        const float* sin = stats + (li - 1) * 16;

        if (tid < 8) {
            float S = aload(&sin[tid]), Q = aload(&sin[8 + tid]);
            float m  = S * (1.0f / 2048.0f);
            float vv = Q * (1.0f / 2048.0f) - m * m;
            float rs = rsqrtf(vv + 1e-5f);
            float sc = g[tid] * rs;
            sscale[tid] = sc;
            sshift[tid] = bet[tid] - m * sc;
        }
        __syncthreads();

        // stage sIn[ci][lp][12][12], plane lp <-> id = 4*odh - 2 + lp
        for (int s = tid; s < 9216; s += 256) {
            int ci = s / 1152, r = s % 1152;
            int lp = r / 144, r2 = r % 144;
            int ph = r2 / 12, pw = r2 % 12;
            int id = 4 * odh - 2 + lp, ih = ph - 2, iw = pw - 2;
            float v = 0.0f;
            if ((unsigned)id < 8u && (unsigned)ih < 8u && (unsigned)iw < 8u) {
                float raw = aload(&cur[(size_t)(b * 8 + ci) * 512 + id * 64 + ih * 8 + iw]);
                float t = fmaf(raw, sscale[ci], sshift[ci]);
                v = t > 0.0f ? t : __expf(t) - 1.0f;
            }
            sIn[s] = v;
        }
        __syncthreads();

        float a2 = convs_b[(li - 1) * 8 + co];
        const float* w = convs_w + (size_t)(li - 1) * 8000 + (size_t)co * 1000;
#pragma unroll
        for (int ci = 0; ci < 8; ++ci) {
            const float* sl = sIn + ci * 1152;
            const float* wc = w + ci * 125;
#pragma unroll
            for (int kd = 0; kd < 5; ++kd) {
                int lp = odl + kd;   // (od&3)+kd in 0..7
#pragma unroll
                for (int kh = 0; kh < 5; ++kh) {
                    const float* row = sl + lp * 144 + (oh + kh) * 12 + ow;
                    const float* wr  = wc + kd * 25 + kh * 5;
#pragma unroll
                    for (int kw = 0; kw < 5; ++kw) a2 = fmaf(row[kw], wr[kw], a2);
                }
            }
        }
        astore(&nxt[(size_t)(b * 8 + co) * 512 + s2], a2);
        {
            float sum = a2, sq = a2 * a2;
#pragma unroll
            for (int o = 32; o > 0; o >>= 1) {
                sum += __shfl_down(sum, o, 64);
                sq  += __shfl_down(sq,  o, 64);
            }
            __syncthreads();   // sIn/sred safe to reuse
            if ((tid & 63) == 0) { sred[tid >> 6] = sum; sred[4 + (tid >> 6)] = sq; }
            __syncthreads();
            if (tid == 0) {
                atomicAdd(&stats[li * 16 + co],     sred[0] + sred[1] + sred[2] + sred[3]);
                atomicAdd(&stats[li * 16 + 8 + co], sred[4] + sred[5] + sred[6] + sred[7]);
            }
        }
        grid_barrier(bar + li * 32, bar + li * 32 + 16, NB_TAIL);

        const float* tmp = cur; cur = nxt; nxt = (float*)tmp;
    }

    // ---- final BN + ELU -> d_out (64 blocks x 256 = 16384 elements) -------
    int i = bx * 256 + tid;
    int c = (i >> 9) & 7;
    float S = aload(&stats[96 + c]), Q = aload(&stats[96 + 8 + c]);
    float m  = S * (1.0f / 2048.0f);
    float vv = Q * (1.0f / 2048.0f) - m * m;
    float rs = rsqrtf(vv + 1e-5f);
    float sc = bns_g[5 * 8 + c] * rs;
    float sh = bns_b[5 * 8 + c] - m * sc;
    float t = fmaf(aload(&cur[i]), sc, sh);
    outp[i] = t > 0.0f ? t : __expf(t) - 1.0f;   // plain store: kernel-end release
}

// ---------------------------------------------------------------------------
extern "C" void kernel_launch(void* const* d_in, const int* in_sizes, int n_in,
                              void* d_out, int out_size, void* d_ws, size_t ws_size,
                              hipStream_t stream)
{
    const float* goals       = (const float*)d_in[0];
    const float* inputs      = (const float*)d_in[1];
    const float* backgrounds = (const float*)d_in[2];
    const float* W1 = (const float*)d_in[3];
    const float* b1 = (const float*)d_in[4];
    const float* W2 = (const float*)d_in[5];
    const float* b2 = (const float*)d_in[6];
    const float* W3 = (const float*)d_in[7];
    const float* b3 = (const float*)d_in[8];
    const float* conv1_w = (const float*)d_in[9];
    const float* conv1_b = (const float*)d_in[10];
    const float* bn1_g   = (const float*)d_in[11];
    const float* bn1_b   = (const float*)d_in[12];
    const float* convs_w = (const float*)d_in[13];
    const float* convs_b = (const float*)d_in[14];
    const float* bns_g   = (const float*)d_in[15];
    const float* bns_b   = (const float*)d_in[16];

    const size_t need8 = ((size_t)NREP * SCENE_FLOATS + 2 * 16384 + 112 + 256) * 4;
    int nrep   = (ws_size >= need8) ? NREP : 1;
    int lscope = (nrep == NREP) ? 1 : 0;   // XCD-local atomics need rep==XCD

    float* wsp     = (float*)d_ws;
    float* scenesR = wsp;                                   // nrep * 162000
    float* yA      = scenesR + (size_t)nrep * SCENE_FLOATS; // 16384
    float* yB      = yA + 16384;                            // 16384
    float* stats   = yB + 16384;                            // 7*16 floats
    unsigned* bar  = (unsigned*)(stats + 7 * 16);           // 7*32 u32 slots

    hipMemsetAsync(scenesR, 0, (size_t)nrep * SCENE_FLOATS * sizeof(float), stream);
    hipMemsetAsync(stats, 0, (7 * 16) * sizeof(float) + 256 * sizeof(unsigned), stream);

    dim3 pgrid((NPTS + 255) / 256, B, 3);
    point_kernel<<<pgrid, 256, 0, stream>>>(inputs, goals, backgrounds,
                                            W1, b1, W2, b2, W3, b3,
                                            scenesR, nrep, lscope);

    tail_kernel<<<NB_TAIL, 256, 0, stream>>>(scenesR, nrep,
                                             conv1_w, conv1_b, bn1_g, bn1_b,
                                             convs_w, convs_b, bns_g, bns_b,
                                             yA, yB, stats, bar, (float*)d_out);
}